// Round 7
// baseline (77.631 us; speedup 1.0000x reference)
//
#include <hip/hip_runtime.h>
#include <cstddef>
#include <cstdint>

#define Bq 64
#define Tq 90
#define Oq 5
#define Dq 256
#define Hq 256
#define EAq 4096
#define Rq 5
#define NBq 8
#define NPGq 95
#define Nq 6080           // B*NPG real nodes
#define NPq 6144          // padded node space: 64 graphs x 96
#define EPBq 4546         // EA + T*O
#define Eq 290944         // B*EPB
#define KKq 1536          // (R+1)*D rows of WT / xwT
#define KAq 480           // A2 cols: 5 relations x 96

typedef __attribute__((ext_vector_type(8))) short bf16x8;
typedef __attribute__((ext_vector_type(8))) unsigned short u16x8;
typedef __attribute__((ext_vector_type(4))) float f32x4;
typedef __attribute__((address_space(1))) const unsigned int gu32;
typedef __attribute__((address_space(3))) unsigned int lu32;

__device__ __forceinline__ unsigned short f2bf(float f) {
    unsigned u = __float_as_uint(f);
    unsigned r = (u + 0x7FFF + ((u >> 16) & 1)) >> 16;
    return (unsigned short)r;
}
__device__ __forceinline__ float bf2f(unsigned short s) {
    return __uint_as_float(((unsigned)s) << 16);
}

// ---------------- fused prep:
// blocks 0..2879: zero A2f; 2880..3647: x->xb bf16; 3648..3695: Wt compute
__global__ __launch_bounds__(256) void k_prep(const float* __restrict__ x,
                                              const float* __restrict__ bases,
                                              const float* __restrict__ comp,
                                              const float* __restrict__ rootw,
                                              unsigned short* __restrict__ xb,
                                              unsigned short* __restrict__ Wt,
                                              float* __restrict__ A2f) {
    __shared__ float Ld[32][257];
    int blk = blockIdx.x;
    if (blk < 2880) {
        unsigned i = blk * 256 + threadIdx.x;       // 737280 float4s == 11,796,480 B
        ((float4*)A2f)[i] = make_float4(0.f, 0.f, 0.f, 0.f);
        return;
    }
    if (blk < 3648) {
        unsigned i = (blk - 2880) * 256 + threadIdx.x;  // over NPq*32 chunks of 8
        unsigned np = i >> 5, c = i & 31;
        unsigned s = np % 96;
        u16x8 pk;
        if (s == 95) {
#pragma unroll
            for (int q = 0; q < 8; ++q) pk[q] = 0;
        } else {
            unsigned node = np - np / 96;
            const float4* xs = (const float4*)(x + (size_t)node * Dq + c * 8);
            float4 a = xs[0], b2 = xs[1];
            pk[0] = f2bf(a.x);  pk[1] = f2bf(a.y);  pk[2] = f2bf(a.z);  pk[3] = f2bf(a.w);
            pk[4] = f2bf(b2.x); pk[5] = f2bf(b2.y); pk[6] = f2bf(b2.z); pk[7] = f2bf(b2.w);
        }
        *(u16x8*)(xb + (size_t)np * Dq + c * 8) = pk;
        return;
    }
    // Wt: WT[kk][d] bf16; kk=r*256+h or 1280+h (root)
    int wblk = blk - 3648;            // 0..47
    int rs = wblk >> 3;               // 0..5
    int d0 = (wblk & 7) * 32;
    int t = threadIdx.x;              // h
    float cmp[NBq];
    if (rs < Rq)
#pragma unroll
        for (int nb = 0; nb < NBq; ++nb) cmp[nb] = comp[rs * NBq + nb];
    for (int dl = 0; dl < 32; ++dl) {
        int d = d0 + dl;
        float v;
        if (rs < Rq) {
            v = 0.f;
#pragma unroll
            for (int nb = 0; nb < NBq; ++nb)
                v += cmp[nb] * bases[((size_t)nb * Dq + d) * Hq + t];
        } else {
            v = rootw[(size_t)d * Hq + t];
        }
        Ld[dl][t] = v;
    }
    __syncthreads();
    int c = t & 31, hg = t >> 5;
    for (int hh = 0; hh < 32; ++hh) {
        int h = hg * 32 + hh;
        Wt[(size_t)(rs * 256 + h) * Dq + d0 + c] = f2bf(Ld[c][h]);
    }
}

// ---------------- fused: P_b = M_b @ Ws^T (bf16 MFMA), column softmax, emit alphaT[b][s][t]
__global__ __launch_bounds__(256) void k_attn(const float* __restrict__ M,
                                              const float* __restrict__ Ws,
                                              float* __restrict__ alphaT) {
    __shared__ __attribute__((aligned(16))) char lds[99072];
    unsigned short* Mb = (unsigned short*)lds;           // [96][256] bf16, swizzled (48KB)
    unsigned short* Wb = (unsigned short*)(lds + 49152); // [96][256] bf16, swizzled (48KB)
    float* P   = (float*)lds;                            // [96][97] fp32 (reuses Mb region)
    float* mxs = (float*)(lds + 98304);                  // [96]
    float* rds = (float*)(lds + 98688);                  // [96]
    const int b = blockIdx.x;
    const int tid = threadIdx.x;

#pragma unroll
    for (int i = 0; i < 12; ++i) {
        int idx = tid + i * 256;            // 0..3071
        int row = idx >> 5, c = idx & 31;
        u16x8 pm, pw;
        if (row < Tq) {
            const float4* ms = (const float4*)(M + ((size_t)b * Tq + row) * Dq + c * 8);
            float4 a0 = ms[0], a1 = ms[1];
            pm[0] = f2bf(a0.x); pm[1] = f2bf(a0.y); pm[2] = f2bf(a0.z); pm[3] = f2bf(a0.w);
            pm[4] = f2bf(a1.x); pm[5] = f2bf(a1.y); pm[6] = f2bf(a1.z); pm[7] = f2bf(a1.w);
            const float4* ws = (const float4*)(Ws + (size_t)row * Dq + c * 8);
            float4 w0 = ws[0], w1 = ws[1];
            pw[0] = f2bf(w0.x); pw[1] = f2bf(w0.y); pw[2] = f2bf(w0.z); pw[3] = f2bf(w0.w);
            pw[4] = f2bf(w1.x); pw[5] = f2bf(w1.y); pw[6] = f2bf(w1.z); pw[7] = f2bf(w1.w);
        } else {
#pragma unroll
            for (int q = 0; q < 8; ++q) { pm[q] = 0; pw[q] = 0; }
        }
        int off = row * 512 + ((c * 16) ^ ((row & 7) << 4));
        *(u16x8*)((char*)Mb + off) = pm;
        *(u16x8*)((char*)Wb + off) = pw;
    }
    __syncthreads();

    const int w = tid >> 6, l = tid & 63;
    const int wr = w >> 1, wc = w & 1;
    f32x4 acc[3][3];
#pragma unroll
    for (int i = 0; i < 3; ++i)
#pragma unroll
        for (int j = 0; j < 3; ++j) acc[i][j] = (f32x4)0.0f;
#pragma unroll
    for (int ks = 0; ks < 8; ++ks) {
        int kb = ks * 64 + (l >> 4) * 16;
        bf16x8 af[3], bfv[3];
#pragma unroll
        for (int mi = 0; mi < 3; ++mi) {
            int row = wr * 48 + mi * 16 + (l & 15);
            af[mi] = *(const bf16x8*)((char*)Mb + row * 512 + (kb ^ ((row & 7) << 4)));
        }
#pragma unroll
        for (int ni = 0; ni < 3; ++ni) {
            int row = wc * 48 + ni * 16 + (l & 15);
            bfv[ni] = *(const bf16x8*)((char*)Wb + row * 512 + (kb ^ ((row & 7) << 4)));
        }
#pragma unroll
        for (int mi = 0; mi < 3; ++mi)
#pragma unroll
            for (int ni = 0; ni < 3; ++ni)
                acc[mi][ni] = __builtin_amdgcn_mfma_f32_16x16x32_bf16(
                    af[mi], bfv[ni], acc[mi][ni], 0, 0, 0);
    }
    __syncthreads();   // all MFMA reads of Mb/Wb done; reuse region for P

#pragma unroll
    for (int mi = 0; mi < 3; ++mi)
#pragma unroll
        for (int ni = 0; ni < 3; ++ni)
#pragma unroll
            for (int j = 0; j < 4; ++j) {
                int rowp = wr * 48 + mi * 16 + (l >> 4) * 4 + j;
                int colp = wc * 48 + ni * 16 + (l & 15);
                P[rowp * 97 + colp] = acc[mi][ni][j];
            }
    __syncthreads();

    if (tid < 96) {
        float m = -1e30f;
        for (int t = 0; t < Tq; ++t) m = fmaxf(m, P[t * 97 + tid]);
        float s = 0.f;
        for (int t = 0; t < Tq; ++t) s += __expf(P[t * 97 + tid] - m);
        mxs[tid] = m;
        rds[tid] = 1.f / s;
    }
    __syncthreads();

#pragma unroll
    for (int i = 0; i < 36; ++i) {
        int idx = tid + i * 256;            // 0..9215
        int s = idx / 96, t = idx - s * 96;
        float v = (t < Tq) ? __expf(P[t * 97 + s] - mxs[s]) * rds[s] : 0.f;
        alphaT[((size_t)b * 96 + s) * 96 + t] = v;
    }
}

// ---------------- wide scatter: norms into A2f[b][dst][r*96+src] (all 256 CUs)
__global__ void k_edges(const float* __restrict__ alphaT, const float* __restrict__ natt,
                        const int* __restrict__ esrc, const int* __restrict__ edst,
                        const int* __restrict__ etype, float* __restrict__ A2f) {
    int e = blockIdx.x * blockDim.x + threadIdx.x;
    if (e >= Eq) return;
    int b = e / EPBq, j = e % EPBq;
    if (j < EAq) {
        int s  = esrc[(size_t)b * EAq + j];
        int dt = edst[(size_t)b * EAq + j];
        int r  = etype[(size_t)b * EAq + j];
        float v = alphaT[((size_t)b * 96 + s) * 96 + dt];
        atomicAdd(&A2f[((size_t)b * 96 + dt) * KAq + r * 96 + s], v);
    } else {
        int i = j - EAq;
        int t = i / Oq, o = i % Oq;
        // tag rows (90..94) / cols disjoint & unique: plain store
        A2f[((size_t)b * 96 + Tq + o) * KAq + (Rq - 1) * 96 + t] =
            natt[(size_t)b * (Tq * Oq) + i];
    }
}

// ---------------- A2f fp32 -> A2b bf16
__global__ void k_a2bf(const float* __restrict__ A2f, unsigned short* __restrict__ A2b) {
    unsigned i = blockIdx.x * blockDim.x + threadIdx.x;   // over 64*96*480/8
    if (i >= (Bq * 96 * KAq) / 8) return;
    const float4* s4 = (const float4*)(A2f + (size_t)i * 8);
    float4 a = s4[0], c = s4[1];
    u16x8 pk;
    pk[0] = f2bf(a.x); pk[1] = f2bf(a.y); pk[2] = f2bf(a.z); pk[3] = f2bf(a.w);
    pk[4] = f2bf(c.x); pk[5] = f2bf(c.y); pk[6] = f2bf(c.z); pk[7] = f2bf(c.w);
    *(u16x8*)(A2b + (size_t)i * 8) = pk;
}

// ---------------- xwT[kk][n'] = sum_d WT[kk][d] * xb[n'][d]   (bf16 MFMA, 64x64, K=256, dbuf)
__global__ __launch_bounds__(256) void k_gemm1(const unsigned short* __restrict__ Wt,
                                               const unsigned short* __restrict__ xb,
                                               unsigned short* __restrict__ xwT) {
    __shared__ float4 lds4[2][1024];    // per buf: As 8KB @0, Bs 8KB @8192
    const int tid = threadIdx.x;
    const int m0 = blockIdx.x * 64, n0 = blockIdx.y * 64;
    const int w = tid >> 6, l = tid & 63;
    const int wr = w >> 1, wc = w & 1;
    const int srow = tid >> 3;
    const int sc = tid & 7;

    f32x4 acc[2][2];
#pragma unroll
    for (int i = 0; i < 2; ++i)
#pragma unroll
        for (int j = 0; j < 2; ++j) acc[i][j] = (f32x4)0.0f;

    char* const lbase0 = (char*)&lds4[0][0];
    char* const lbase1 = (char*)&lds4[1][0];

    auto stage = [&](char* base, int k0) {
#pragma unroll
        for (int i = 0; i < 2; ++i) {
            int row = i * 32 + srow;
            int csrc = sc ^ (row & 7);
            const unsigned short* g = Wt + (size_t)(m0 + row) * Dq + k0 + csrc * 8;
            char* ld = base + i * 4096 + w * 1024;
            __builtin_amdgcn_global_load_lds((gu32*)g, (lu32*)(unsigned int)(uintptr_t)ld, 16, 0, 0);
        }
#pragma unroll
        for (int i = 0; i < 2; ++i) {
            int row = i * 32 + srow;
            int csrc = sc ^ (row & 7);
            const unsigned short* g = xb + (size_t)(n0 + row) * Dq + k0 + csrc * 8;
            char* ld = base + 8192 + i * 4096 + w * 1024;
            __builtin_amdgcn_global_load_lds((gu32*)g, (lu32*)(unsigned int)(uintptr_t)ld, 16, 0, 0);
        }
    };

    stage(lbase0, 0);
    __syncthreads();

    int cur = 0;
    for (int t = 0; t < Dq / 64; ++t) {
        char* base = cur ? lbase1 : lbase0;
        if (t < Dq / 64 - 1) stage(cur ? lbase0 : lbase1, (t + 1) * 64);

        bf16x8 af[2][2], bfr[2][2];
#pragma unroll
        for (int ks = 0; ks < 2; ++ks) {
            int koff = ks * 64 + (l >> 4) * 16;
#pragma unroll
            for (int mi = 0; mi < 2; ++mi) {
                int row = wr * 32 + mi * 16 + (l & 15);
                af[mi][ks] = *(const bf16x8*)(base + row * 128 + (koff ^ ((row & 7) << 4)));
            }
#pragma unroll
            for (int ni = 0; ni < 2; ++ni) {
                int row = wc * 32 + ni * 16 + (l & 15);
                bfr[ni][ks] = *(const bf16x8*)(base + 8192 + row * 128 + (koff ^ ((row & 7) << 4)));
            }
        }
#pragma unroll
        for (int ks = 0; ks < 2; ++ks)
#pragma unroll
            for (int mi = 0; mi < 2; ++mi)
#pragma unroll
                for (int ni = 0; ni < 2; ++ni)
                    acc[mi][ni] = __builtin_amdgcn_mfma_f32_16x16x32_bf16(
                        af[mi][ks], bfr[ni][ks], acc[mi][ni], 0, 0, 0);
        __syncthreads();
        cur ^= 1;
    }

    // LDS-bounce epilogue: per-wave [32][33] fp32 scratch -> row-contiguous bf16 stores
    float* epi = (float*)lbase0 + w * 1056;    // 32*33 floats per wave
#pragma unroll
    for (int mi = 0; mi < 2; ++mi)
#pragma unroll
        for (int ni = 0; ni < 2; ++ni)
#pragma unroll
            for (int j = 0; j < 4; ++j) {
                int row = mi * 16 + (l >> 4) * 4 + j;
                int col = ni * 16 + (l & 15);
                epi[row * 33 + col] = acc[mi][ni][j];
            }
    int c = l & 31, half = l >> 5;
    u16x8 o0, o1;
#pragma unroll
    for (int q = 0; q < 8; ++q) o0[q] = f2bf(epi[c * 33 + half * 16 + q]);
#pragma unroll
    for (int q = 0; q < 8; ++q) o1[q] = f2bf(epi[c * 33 + half * 16 + 8 + q]);
    unsigned short* dst = xwT + (size_t)(m0 + wr * 32 + c) * NPq + n0 + wc * 32 + half * 16;
    *(u16x8*)dst = o0;
    *(u16x8*)(dst + 8) = o1;
}

// ---------------- out[b*95+nl][h] = sum_k A2b[b][nl][k] * Ychunk + root + bias
__global__ __launch_bounds__(256) void k_gemm2(const unsigned short* __restrict__ A2b,
                                               const unsigned short* __restrict__ xwT,
                                               const float* __restrict__ bias,
                                               float* __restrict__ out) {
    __shared__ char lds[2][30720];      // per buf: A 96x96 bf16 (18432) + Y 64x96 bf16 (12288)
    const int tid = threadIdx.x;
    const int b = blockIdx.x;
    const int h0 = blockIdx.y * 64;
    const int w = tid >> 6, l = tid & 63;
    const int wr = w >> 1, wc = w & 1;

    f32x4 acc[3][2];
#pragma unroll
    for (int i = 0; i < 3; ++i)
#pragma unroll
        for (int j = 0; j < 2; ++j) acc[i][j] = (f32x4)0.0f;

    auto stage = [&](int buf, int r) {
        char* base = &lds[buf][0];
#pragma unroll
        for (int i = 0; i < 5; ++i) {
            unsigned idx = tid + i * 256;
            if (idx < 1152) {
                unsigned row = idx / 12, u = idx - row * 12;
                unsigned usw = u ^ (row & 3);
                const unsigned short* g = A2b + ((size_t)b * 96 + row) * KAq + r * 96 + usw * 8;
                __builtin_amdgcn_global_load_lds((gu32*)g,
                    (lu32*)(unsigned int)(uintptr_t)(base + idx * 16), 16, 0, 0);
            }
        }
#pragma unroll
        for (int i = 0; i < 3; ++i) {
            unsigned idx = tid + i * 256;
            unsigned row = idx / 12, u = idx - row * 12;
            unsigned usw = u ^ (row & 3);
            const unsigned short* g = xwT + (size_t)(r * 256 + h0 + row) * NPq + b * 96 + usw * 8;
            __builtin_amdgcn_global_load_lds((gu32*)g,
                (lu32*)(unsigned int)(uintptr_t)(base + 18432 + idx * 16), 16, 0, 0);
        }
    };

    stage(0, 0);
    __syncthreads();
    int cur = 0;
    for (int r = 0; r < 5; ++r) {
        char* base = &lds[cur][0];
        if (r < 4) stage(cur ^ 1, r + 1);
        bf16x8 af[3], bfv[2];
#pragma unroll
        for (int ks = 0; ks < 3; ++ks) {
            int kb = ks * 64 + (l >> 4) * 16;
#pragma unroll
            for (int mi = 0; mi < 3; ++mi) {
                int row = wr * 48 + mi * 16 + (l & 15);
                af[mi] = *(const bf16x8*)(base + row * 192 + (kb ^ ((row & 3) << 4)));
            }
#pragma unroll
            for (int ni = 0; ni < 2; ++ni) {
                int row = wc * 32 + ni * 16 + (l & 15);
                bfv[ni] = *(const bf16x8*)(base + 18432 + row * 192 + (kb ^ ((row & 3) << 4)));
            }
#pragma unroll
            for (int mi = 0; mi < 3; ++mi)
#pragma unroll
                for (int ni = 0; ni < 2; ++ni)
                    acc[mi][ni] = __builtin_amdgcn_mfma_f32_16x16x32_bf16(
                        af[mi], bfv[ni], acc[mi][ni], 0, 0, 0);
        }
        __syncthreads();
        cur ^= 1;
    }

#pragma unroll
    for (int mi = 0; mi < 3; ++mi) {
        int mrow = wr * 48 + mi * 16 + (l >> 4) * 4;
#pragma unroll
        for (int ni = 0; ni < 2; ++ni) {
            int n = h0 + wc * 32 + ni * 16 + (l & 15);
            float bv = bias[n];
            ushort4 rt = *(const ushort4*)(xwT + (size_t)(Rq * 256 + n) * NPq + b * 96 + mrow);
#pragma unroll
            for (int j = 0; j < 4; ++j) {
                int m = mrow + j;
                float rv = bf2f(j == 0 ? rt.x : j == 1 ? rt.y : j == 2 ? rt.z : rt.w);
                if (m < NPGq)
                    out[((size_t)b * NPGq + m) * Hq + n] = acc[mi][ni][j] + rv + bv;
            }
        }
    }
}

extern "C" void kernel_launch(void* const* d_in, const int* in_sizes, int n_in,
                              void* d_out, int out_size, void* d_ws, size_t ws_size,
                              hipStream_t stream) {
    (void)in_sizes; (void)n_in; (void)out_size; (void)ws_size;
    const float* M     = (const float*)d_in[0];
    const float* x     = (const float*)d_in[1];
    const float* natt  = (const float*)d_in[2];
    const float* Ws    = (const float*)d_in[3];
    const float* bases = (const float*)d_in[4];
    const float* comp  = (const float*)d_in[5];
    const float* rootw = (const float*)d_in[6];
    const float* bias  = (const float*)d_in[7];
    const int* esrc    = (const int*)d_in[8];
    const int* edst    = (const int*)d_in[9];
    const int* etype   = (const int*)d_in[10];
    float* out = (float*)d_out;
    char* ws = (char*)d_ws;

    unsigned short* Wt  = (unsigned short*)(ws + 0);          //    786,432 B
    float* alphaT = (float*)(ws + 786432);                    //  2,359,296 B
    float* A2f   = (float*)(ws + 3145728);                    // 11,796,480 B
    unsigned short* A2b = (unsigned short*)(ws + 14942208);   //  5,898,240 B
    unsigned short* xb  = (unsigned short*)(ws + 20840448);   //  3,145,728 B
    unsigned short* xwT = (unsigned short*)(ws + 23986176);   // 18,874,368 B (total ~42.9 MB)

    k_prep<<<dim3(3696), 256, 0, stream>>>(x, bases, comp, rootw, xb, Wt, A2f);
    k_attn<<<dim3(Bq), 256, 0, stream>>>(M, Ws, alphaT);
    k_edges<<<dim3((Eq + 255) / 256), 256, 0, stream>>>(alphaT, natt, esrc, edst, etype, A2f);
    k_a2bf<<<dim3((Bq * 96 * KAq / 8 + 255) / 256), 256, 0, stream>>>(A2f, A2b);
    k_gemm1<<<dim3(KKq / 64, NPq / 64), 256, 0, stream>>>(Wt, xb, xwT);
    k_gemm2<<<dim3(Bq, Hq / 64), 256, 0, stream>>>(A2b, xwT, bias, out);
}

// Round 8
// 70.805 us; speedup vs baseline: 1.0964x; 1.0964x over previous
//
#include <hip/hip_runtime.h>
#include <cstddef>
#include <cstdint>

#define Bq 64
#define Tq 90
#define Oq 5
#define Dq 256
#define Hq 256
#define EAq 4096
#define Rq 5
#define NBq 8
#define NPGq 95
#define Nq 6080           // B*NPG real nodes
#define NPq 6144          // padded node space: 64 graphs x 96
#define EPBq 4546         // EA + T*O
#define Eq 290944         // B*EPB
#define KKq 1536          // (R+1)*D rows of WT / xwT
#define KAq 480           // A2 cols: 5 relations x 96

typedef __attribute__((ext_vector_type(8))) short bf16x8;
typedef __attribute__((ext_vector_type(8))) unsigned short u16x8;
typedef __attribute__((ext_vector_type(4))) float f32x4;
typedef __attribute__((address_space(1))) const unsigned int gu32;
typedef __attribute__((address_space(3))) unsigned int lu32;

__device__ __forceinline__ unsigned short f2bf(float f) {
    unsigned u = __float_as_uint(f);
    unsigned r = (u + 0x7FFF + ((u >> 16) & 1)) >> 16;
    return (unsigned short)r;
}
__device__ __forceinline__ float bf2f(unsigned short s) {
    return __uint_as_float(((unsigned)s) << 16);
}

// ---------------- fused prep:
// blocks 0..2879: zero A2f; 2880..3647: x->xb bf16; 3648..3695: Wt compute
__global__ __launch_bounds__(256) void k_prep(const float* __restrict__ x,
                                              const float* __restrict__ bases,
                                              const float* __restrict__ comp,
                                              const float* __restrict__ rootw,
                                              unsigned short* __restrict__ xb,
                                              unsigned short* __restrict__ Wt,
                                              float* __restrict__ A2f) {
    __shared__ float Ld[32][257];
    int blk = blockIdx.x;
    if (blk < 2880) {
        unsigned i = blk * 256 + threadIdx.x;       // 737280 float4s == 11,796,480 B
        ((float4*)A2f)[i] = make_float4(0.f, 0.f, 0.f, 0.f);
        return;
    }
    if (blk < 3648) {
        unsigned i = (blk - 2880) * 256 + threadIdx.x;  // over NPq*32 chunks of 8
        unsigned np = i >> 5, c = i & 31;
        unsigned s = np % 96;
        u16x8 pk;
        if (s == 95) {
#pragma unroll
            for (int q = 0; q < 8; ++q) pk[q] = 0;
        } else {
            unsigned node = np - np / 96;
            const float4* xs = (const float4*)(x + (size_t)node * Dq + c * 8);
            float4 a = xs[0], b2 = xs[1];
            pk[0] = f2bf(a.x);  pk[1] = f2bf(a.y);  pk[2] = f2bf(a.z);  pk[3] = f2bf(a.w);
            pk[4] = f2bf(b2.x); pk[5] = f2bf(b2.y); pk[6] = f2bf(b2.z); pk[7] = f2bf(b2.w);
        }
        *(u16x8*)(xb + (size_t)np * Dq + c * 8) = pk;
        return;
    }
    // Wt: WT[kk][d] bf16; kk=r*256+h or 1280+h (root)
    int wblk = blk - 3648;            // 0..47
    int rs = wblk >> 3;               // 0..5
    int d0 = (wblk & 7) * 32;
    int t = threadIdx.x;              // h
    float cmp[NBq];
    if (rs < Rq)
#pragma unroll
        for (int nb = 0; nb < NBq; ++nb) cmp[nb] = comp[rs * NBq + nb];
    for (int dl = 0; dl < 32; ++dl) {
        int d = d0 + dl;
        float v;
        if (rs < Rq) {
            v = 0.f;
#pragma unroll
            for (int nb = 0; nb < NBq; ++nb)
                v += cmp[nb] * bases[((size_t)nb * Dq + d) * Hq + t];
        } else {
            v = rootw[(size_t)d * Hq + t];
        }
        Ld[dl][t] = v;
    }
    __syncthreads();
    int c = t & 31, hg = t >> 5;
    for (int hh = 0; hh < 32; ++hh) {
        int h = hg * 32 + hh;
        Wt[(size_t)(rs * 256 + h) * Dq + d0 + c] = f2bf(Ld[c][h]);
    }
}

// ---------------- fused: P_b = M_b @ Ws^T (bf16 MFMA, 9 waves, 32x32 quadrants),
//                  column softmax, scatter edge norms into A2f[b] in-block
__global__ __launch_bounds__(576) void k_attn(const float* __restrict__ M,
                                              const float* __restrict__ Ws,
                                              const float* __restrict__ natt,
                                              const int* __restrict__ esrc,
                                              const int* __restrict__ edst,
                                              const int* __restrict__ etype,
                                              float* __restrict__ A2f) {
    __shared__ __attribute__((aligned(16))) char lds[99072];
    unsigned short* Mb = (unsigned short*)lds;           // [96][256] bf16, swizzled (48KB)
    unsigned short* Wb = (unsigned short*)(lds + 49152); // [96][256] bf16, swizzled (48KB)
    float* P   = (float*)lds;                            // [96][97] fp32 (reuses Mb region)
    float* mxs = (float*)(lds + 98304);                  // [96]
    float* rds = (float*)(lds + 98688);                  // [96]
    const int b = blockIdx.x;
    const int tid = threadIdx.x;

    // stage M[b] and Ws as bf16 with XOR swizzle; rows 90..95 zero (6 iters/thread)
#pragma unroll
    for (int i = 0; i < 6; ++i) {
        int idx = tid + i * 576;            // 0..3455, want 0..3071
        if (idx < 3072) {
            int row = idx >> 5, c = idx & 31;
            u16x8 pm, pw;
            if (row < Tq) {
                const float4* ms = (const float4*)(M + ((size_t)b * Tq + row) * Dq + c * 8);
                float4 a0 = ms[0], a1 = ms[1];
                pm[0] = f2bf(a0.x); pm[1] = f2bf(a0.y); pm[2] = f2bf(a0.z); pm[3] = f2bf(a0.w);
                pm[4] = f2bf(a1.x); pm[5] = f2bf(a1.y); pm[6] = f2bf(a1.z); pm[7] = f2bf(a1.w);
                const float4* ws = (const float4*)(Ws + (size_t)row * Dq + c * 8);
                float4 w0 = ws[0], w1 = ws[1];
                pw[0] = f2bf(w0.x); pw[1] = f2bf(w0.y); pw[2] = f2bf(w0.z); pw[3] = f2bf(w0.w);
                pw[4] = f2bf(w1.x); pw[5] = f2bf(w1.y); pw[6] = f2bf(w1.z); pw[7] = f2bf(w1.w);
            } else {
#pragma unroll
                for (int q = 0; q < 8; ++q) { pm[q] = 0; pw[q] = 0; }
            }
            int off = row * 512 + ((c * 16) ^ ((row & 7) << 4));
            *(u16x8*)((char*)Mb + off) = pm;
            *(u16x8*)((char*)Wb + off) = pw;
        }
    }
    __syncthreads();

    // 9 waves: wave w owns 32x32 quadrant (wr,wc) = (w/3, w%3); 2x2 frags of 16x16
    const int w = tid >> 6, l = tid & 63;
    const int wr = w / 3, wc = w % 3;
    f32x4 acc[2][2];
#pragma unroll
    for (int i = 0; i < 2; ++i)
#pragma unroll
        for (int j = 0; j < 2; ++j) acc[i][j] = (f32x4)0.0f;
#pragma unroll
    for (int ks = 0; ks < 8; ++ks) {
        int kb = ks * 64 + (l >> 4) * 16;
        bf16x8 af[2], bfv[2];
#pragma unroll
        for (int mi = 0; mi < 2; ++mi) {
            int row = wr * 32 + mi * 16 + (l & 15);
            af[mi] = *(const bf16x8*)((char*)Mb + row * 512 + (kb ^ ((row & 7) << 4)));
        }
#pragma unroll
        for (int ni = 0; ni < 2; ++ni) {
            int row = wc * 32 + ni * 16 + (l & 15);
            bfv[ni] = *(const bf16x8*)((char*)Wb + row * 512 + (kb ^ ((row & 7) << 4)));
        }
#pragma unroll
        for (int mi = 0; mi < 2; ++mi)
#pragma unroll
            for (int ni = 0; ni < 2; ++ni)
                acc[mi][ni] = __builtin_amdgcn_mfma_f32_16x16x32_bf16(
                    af[mi], bfv[ni], acc[mi][ni], 0, 0, 0);
    }
    __syncthreads();   // all MFMA reads of Mb/Wb done; reuse region for P

#pragma unroll
    for (int mi = 0; mi < 2; ++mi)
#pragma unroll
        for (int ni = 0; ni < 2; ++ni)
#pragma unroll
            for (int j = 0; j < 4; ++j) {
                int rowp = wr * 32 + mi * 16 + (l >> 4) * 4 + j;
                int colp = wc * 32 + ni * 16 + (l & 15);
                P[rowp * 97 + colp] = acc[mi][ni][j];
            }
    __syncthreads();

    if (tid < 96) {
        float m = -1e30f;
        for (int t = 0; t < Tq; ++t) m = fmaxf(m, P[t * 97 + tid]);
        float s = 0.f;
        for (int t = 0; t < Tq; ++t) s += __expf(P[t * 97 + tid] - m);
        mxs[tid] = m;
        rds[tid] = 1.f / s;
    }
    __syncthreads();

    // edge scatter for this graph (4546 edges, 8 iters/thread)
    for (int j = tid; j < EPBq; j += 576) {
        if (j < EAq) {
            int s  = esrc[(size_t)b * EAq + j];
            int dt = edst[(size_t)b * EAq + j];
            int r  = etype[(size_t)b * EAq + j];
            float v = __expf(P[dt * 97 + s] - mxs[s]) * rds[s];
            atomicAdd(&A2f[((size_t)b * 96 + dt) * KAq + r * 96 + s], v);
        } else {
            int i = j - EAq;
            int t = i / Oq, o = i % Oq;
            A2f[((size_t)b * 96 + Tq + o) * KAq + (Rq - 1) * 96 + t] =
                natt[(size_t)b * (Tq * Oq) + i];
        }
    }
}

// ---------------- A2f fp32 -> A2b bf16
__global__ void k_a2bf(const float* __restrict__ A2f, unsigned short* __restrict__ A2b) {
    unsigned i = blockIdx.x * blockDim.x + threadIdx.x;   // over 64*96*480/8
    if (i >= (Bq * 96 * KAq) / 8) return;
    const float4* s4 = (const float4*)(A2f + (size_t)i * 8);
    float4 a = s4[0], c = s4[1];
    u16x8 pk;
    pk[0] = f2bf(a.x); pk[1] = f2bf(a.y); pk[2] = f2bf(a.z); pk[3] = f2bf(a.w);
    pk[4] = f2bf(c.x); pk[5] = f2bf(c.y); pk[6] = f2bf(c.z); pk[7] = f2bf(c.w);
    *(u16x8*)(A2b + (size_t)i * 8) = pk;
}

// ---------------- xwT[kk][n'] = sum_d WT[kk][d] * xb[n'][d]   (bf16 MFMA, 64x64, K=256, dbuf)
__global__ __launch_bounds__(256) void k_gemm1(const unsigned short* __restrict__ Wt,
                                               const unsigned short* __restrict__ xb,
                                               unsigned short* __restrict__ xwT) {
    __shared__ float4 lds4[2][1024];    // per buf: As 8KB @0, Bs 8KB @8192
    const int tid = threadIdx.x;
    const int m0 = blockIdx.x * 64, n0 = blockIdx.y * 64;
    const int w = tid >> 6, l = tid & 63;
    const int wr = w >> 1, wc = w & 1;
    const int srow = tid >> 3;
    const int sc = tid & 7;

    f32x4 acc[2][2];
#pragma unroll
    for (int i = 0; i < 2; ++i)
#pragma unroll
        for (int j = 0; j < 2; ++j) acc[i][j] = (f32x4)0.0f;

    char* const lbase0 = (char*)&lds4[0][0];
    char* const lbase1 = (char*)&lds4[1][0];

    auto stage = [&](char* base, int k0) {
#pragma unroll
        for (int i = 0; i < 2; ++i) {
            int row = i * 32 + srow;
            int csrc = sc ^ (row & 7);
            const unsigned short* g = Wt + (size_t)(m0 + row) * Dq + k0 + csrc * 8;
            char* ld = base + i * 4096 + w * 1024;
            __builtin_amdgcn_global_load_lds((gu32*)g, (lu32*)(unsigned int)(uintptr_t)ld, 16, 0, 0);
        }
#pragma unroll
        for (int i = 0; i < 2; ++i) {
            int row = i * 32 + srow;
            int csrc = sc ^ (row & 7);
            const unsigned short* g = xb + (size_t)(n0 + row) * Dq + k0 + csrc * 8;
            char* ld = base + 8192 + i * 4096 + w * 1024;
            __builtin_amdgcn_global_load_lds((gu32*)g, (lu32*)(unsigned int)(uintptr_t)ld, 16, 0, 0);
        }
    };

    stage(lbase0, 0);
    __syncthreads();

    int cur = 0;
    for (int t = 0; t < Dq / 64; ++t) {
        char* base = cur ? lbase1 : lbase0;
        if (t < Dq / 64 - 1) stage(cur ? lbase0 : lbase1, (t + 1) * 64);

        bf16x8 af[2][2], bfr[2][2];
#pragma unroll
        for (int ks = 0; ks < 2; ++ks) {
            int koff = ks * 64 + (l >> 4) * 16;
#pragma unroll
            for (int mi = 0; mi < 2; ++mi) {
                int row = wr * 32 + mi * 16 + (l & 15);
                af[mi][ks] = *(const bf16x8*)(base + row * 128 + (koff ^ ((row & 7) << 4)));
            }
#pragma unroll
            for (int ni = 0; ni < 2; ++ni) {
                int row = wc * 32 + ni * 16 + (l & 15);
                bfr[ni][ks] = *(const bf16x8*)(base + 8192 + row * 128 + (koff ^ ((row & 7) << 4)));
            }
        }
#pragma unroll
        for (int ks = 0; ks < 2; ++ks)
#pragma unroll
            for (int mi = 0; mi < 2; ++mi)
#pragma unroll
                for (int ni = 0; ni < 2; ++ni)
                    acc[mi][ni] = __builtin_amdgcn_mfma_f32_16x16x32_bf16(
                        af[mi][ks], bfr[ni][ks], acc[mi][ni], 0, 0, 0);
        __syncthreads();
        cur ^= 1;
    }

    // LDS-bounce epilogue: per-wave [32][33] fp32 scratch -> row-contiguous bf16 stores
    float* epi = (float*)lbase0 + w * 1056;    // 32*33 floats per wave
#pragma unroll
    for (int mi = 0; mi < 2; ++mi)
#pragma unroll
        for (int ni = 0; ni < 2; ++ni)
#pragma unroll
            for (int j = 0; j < 4; ++j) {
                int row = mi * 16 + (l >> 4) * 4 + j;
                int col = ni * 16 + (l & 15);
                epi[row * 33 + col] = acc[mi][ni][j];
            }
    int c = l & 31, half = l >> 5;
    u16x8 o0, o1;
#pragma unroll
    for (int q = 0; q < 8; ++q) o0[q] = f2bf(epi[c * 33 + half * 16 + q]);
#pragma unroll
    for (int q = 0; q < 8; ++q) o1[q] = f2bf(epi[c * 33 + half * 16 + 8 + q]);
    unsigned short* dst = xwT + (size_t)(m0 + wr * 32 + c) * NPq + n0 + wc * 32 + half * 16;
    *(u16x8*)dst = o0;
    *(u16x8*)(dst + 8) = o1;
}

// ---------------- out[b*95+nl][h] = sum_k A2b[b][nl][k] * Ychunk + root + bias
__global__ __launch_bounds__(256) void k_gemm2(const unsigned short* __restrict__ A2b,
                                               const unsigned short* __restrict__ xwT,
                                               const float* __restrict__ bias,
                                               float* __restrict__ out) {
    __shared__ char lds[2][30720];      // per buf: A 96x96 bf16 (18432) + Y 64x96 bf16 (12288)
    const int tid = threadIdx.x;
    const int b = blockIdx.x;
    const int h0 = blockIdx.y * 64;
    const int w = tid >> 6, l = tid & 63;
    const int wr = w >> 1, wc = w & 1;

    f32x4 acc[3][2];
#pragma unroll
    for (int i = 0; i < 3; ++i)
#pragma unroll
        for (int j = 0; j < 2; ++j) acc[i][j] = (f32x4)0.0f;

    auto stage = [&](int buf, int r) {
        char* base = &lds[buf][0];
#pragma unroll
        for (int i = 0; i < 5; ++i) {
            unsigned idx = tid + i * 256;
            if (idx < 1152) {
                unsigned row = idx / 12, u = idx - row * 12;
                unsigned usw = u ^ (row & 3);
                const unsigned short* g = A2b + ((size_t)b * 96 + row) * KAq + r * 96 + usw * 8;
                __builtin_amdgcn_global_load_lds((gu32*)g,
                    (lu32*)(unsigned int)(uintptr_t)(base + idx * 16), 16, 0, 0);
            }
        }
#pragma unroll
        for (int i = 0; i < 3; ++i) {
            unsigned idx = tid + i * 256;
            unsigned row = idx / 12, u = idx - row * 12;
            unsigned usw = u ^ (row & 3);
            const unsigned short* g = xwT + (size_t)(r * 256 + h0 + row) * NPq + b * 96 + usw * 8;
            __builtin_amdgcn_global_load_lds((gu32*)g,
                (lu32*)(unsigned int)(uintptr_t)(base + 18432 + idx * 16), 16, 0, 0);
        }
    };

    stage(0, 0);
    __syncthreads();
    int cur = 0;
    for (int r = 0; r < 5; ++r) {
        char* base = &lds[cur][0];
        if (r < 4) stage(cur ^ 1, r + 1);
        bf16x8 af[3], bfv[2];
#pragma unroll
        for (int ks = 0; ks < 3; ++ks) {
            int kb = ks * 64 + (l >> 4) * 16;
#pragma unroll
            for (int mi = 0; mi < 3; ++mi) {
                int row = wr * 48 + mi * 16 + (l & 15);
                af[mi] = *(const bf16x8*)(base + row * 192 + (kb ^ ((row & 3) << 4)));
            }
#pragma unroll
            for (int ni = 0; ni < 2; ++ni) {
                int row = wc * 32 + ni * 16 + (l & 15);
                bfv[ni] = *(const bf16x8*)(base + 18432 + row * 192 + (kb ^ ((row & 3) << 4)));
            }
#pragma unroll
            for (int mi = 0; mi < 3; ++mi)
#pragma unroll
                for (int ni = 0; ni < 2; ++ni)
                    acc[mi][ni] = __builtin_amdgcn_mfma_f32_16x16x32_bf16(
                        af[mi], bfv[ni], acc[mi][ni], 0, 0, 0);
        }
        __syncthreads();
        cur ^= 1;
    }

#pragma unroll
    for (int mi = 0; mi < 3; ++mi) {
        int mrow = wr * 48 + mi * 16 + (l >> 4) * 4;
#pragma unroll
        for (int ni = 0; ni < 2; ++ni) {
            int n = h0 + wc * 32 + ni * 16 + (l & 15);
            float bv = bias[n];
            ushort4 rt = *(const ushort4*)(xwT + (size_t)(Rq * 256 + n) * NPq + b * 96 + mrow);
#pragma unroll
            for (int j = 0; j < 4; ++j) {
                int m = mrow + j;
                float rv = bf2f(j == 0 ? rt.x : j == 1 ? rt.y : j == 2 ? rt.z : rt.w);
                if (m < NPGq)
                    out[((size_t)b * NPGq + m) * Hq + n] = acc[mi][ni][j] + rv + bv;
            }
        }
    }
}

extern "C" void kernel_launch(void* const* d_in, const int* in_sizes, int n_in,
                              void* d_out, int out_size, void* d_ws, size_t ws_size,
                              hipStream_t stream) {
    (void)in_sizes; (void)n_in; (void)out_size; (void)ws_size;
    const float* M     = (const float*)d_in[0];
    const float* x     = (const float*)d_in[1];
    const float* natt  = (const float*)d_in[2];
    const float* Ws    = (const float*)d_in[3];
    const float* bases = (const float*)d_in[4];
    const float* comp  = (const float*)d_in[5];
    const float* rootw = (const float*)d_in[6];
    const float* bias  = (const float*)d_in[7];
    const int* esrc    = (const int*)d_in[8];
    const int* edst    = (const int*)d_in[9];
    const int* etype   = (const int*)d_in[10];
    float* out = (float*)d_out;
    char* ws = (char*)d_ws;

    unsigned short* Wt  = (unsigned short*)(ws + 0);          //    786,432 B
    float* A2f   = (float*)(ws + 786432);                     // 11,796,480 B
    unsigned short* A2b = (unsigned short*)(ws + 12582912);   //  5,898,240 B
    unsigned short* xb  = (unsigned short*)(ws + 18481152);   //  3,145,728 B
    unsigned short* xwT = (unsigned short*)(ws + 21626880);   // 18,874,368 B (total ~40.5 MB)

    k_prep<<<dim3(3696), 256, 0, stream>>>(x, bases, comp, rootw, xb, Wt, A2f);
    k_attn<<<dim3(Bq), 576, 0, stream>>>(M, Ws, natt, esrc, edst, etype, A2f);
    k_a2bf<<<dim3((Bq * 96 * KAq / 8 + 255) / 256), 256, 0, stream>>>(A2f, A2b);
    k_gemm1<<<dim3(KKq / 64, NPq / 64), 256, 0, stream>>>(Wt, xb, xwT);
    k_gemm2<<<dim3(Bq, Hq / 64), 256, 0, stream>>>(A2b, xwT, bias, out);
}